// Round 10
// baseline (81.580 us; speedup 1.0000x reference)
//
#include <hip/hip_runtime.h>

// Soft histogram, fused single dispatch, ZERO float atomics:
//   hist[b,c,j] = (1/P) * sum_pixels f_j(x),  f_j(x) = k_j(x)/(sum_j k_j(x)+1e-12)
// Each block: (1) LDS u32 histogram of its 8192-pixel chunk into 1024 cells;
// (2a) per-cell weight w[q] = n[q]/(banded kernel sum) -- pure compute;
// (2b) per-BIN GATHER over a 384-cell window with the exact scatter
//      predicate (js(q) <= j <= js(q)+15) -- no LDS atomics at all;
// (3) R9-proven handoff: atomicExch to disjoint g_part slots, padded
//      monotonic tickets, last block per image reduces + normalizes.
//
// R2:  two dispatches, disjoint partials.                     90.0 us
// R5:  wide-unroll 256-thr finalize.                          75.7 us
// R7:  fence-free atomic split.                               74.0 us
// R8-R10: fused with LDS float atomicAdd phase 2: 78 us kernel, invariant
//      under handoff (R9) and register (R10) changes.
// R11: split + unsafeAtomicAdd: 74.0 us, ZERO delta -> split is at ITS floor.
//      Budget (3 independent graphs): fill 43.4 + replay ~17.5 (per-GRAPH,
//      same for 2 and 3 dispatches) + kernels ~13. Only kernels controllable.
// R12: last untested suspect for the fused 78 us: 16K LDS float atomicAdd
//      per block = CAS-loop retry storms on 64 hot fh[] addresses
//      (lgkmcnt serialization; invisible to VALUBusy/HBM counters).
//      This version has no float atomics anywhere. Same band math ->
//      same terms, reordered sum only (absmax stays ~1.2e-4).

#define NQ      1024
#define NBINS   64
#define NIMG    24            // B*C = 8*3
#define IMG_PIX (512 * 512)   // 262144 pixels per (b,c) image
#define BPI     32            // count blocks per image
#define CNT_BLOCKS (NIMG * BPI)        // 768
#define WIN     384           // gather window (band ~260 cells + edge clamp)

__device__ float        g_part[CNT_BLOCKS * NBINS];  // disjoint per-block slots
__device__ unsigned int g_ticket[NIMG * 32];         // 128B stride, monotonic

__global__ __launch_bounds__(256) void soft_hist_fused(
    const float* __restrict__ x, const float* __restrict__ centers,
    float* __restrict__ out)
{
    __shared__ unsigned int h[NQ];        // 4 KB  per-cell counts
    __shared__ float        wq[NQ];       // 4 KB  per-cell weights n/s
    __shared__ float        cl[NBINS];    // centers
    __shared__ float        part[4][NBINS];
    __shared__ float        red[4][NBINS];
    __shared__ unsigned int s_last;

    const int bid = blockIdx.x;
    const int t   = threadIdx.x;
    const int img = bid >> 5;             // bid / BPI

    #pragma unroll
    for (int k = 0; k < NQ / 256; ++k) h[t + k * 256] = 0u;
    if (t < NBINS) cl[t] = centers[t];
    __syncthreads();

    // ---- phase 1: histogram 8192 pixels (contiguous 32 KB chunk) ----
    const float4* x4 = (const float4*)x + (size_t)bid * (IMG_PIX / 4 / BPI);
    float4 v[8];
    #pragma unroll
    for (int r = 0; r < 8; ++r) v[r] = x4[r * 256 + t];

    #pragma unroll
    for (int r = 0; r < 8; ++r) {
        const float4 p = v[r];
        int q0 = (int)(p.x * (float)NQ); q0 = q0 < 0 ? 0 : (q0 > NQ - 1 ? NQ - 1 : q0);
        int q1 = (int)(p.y * (float)NQ); q1 = q1 < 0 ? 0 : (q1 > NQ - 1 ? NQ - 1 : q1);
        int q2 = (int)(p.z * (float)NQ); q2 = q2 < 0 ? 0 : (q2 > NQ - 1 ? NQ - 1 : q2);
        int q3 = (int)(p.w * (float)NQ); q3 = q3 < 0 ? 0 : (q3 > NQ - 1 ? NQ - 1 : q3);
        atomicAdd(&h[q0], 1u);   // u32 LDS atomics: native HW op
        atomicAdd(&h[q1], 1u);
        atomicAdd(&h[q2], 1u);
        atomicAdd(&h[q3], 1u);
    }
    __syncthreads();

    // ---- phase 2a: per-cell weight w[q] = n / (banded kernel sum) ----
    // Identical normalization expression to the verified scatter version.
    #pragma unroll
    for (int k = 0; k < 4; ++k) {
        const int   q  = t + k * 256;
        const float n  = (float)h[q];
        const float cq = ((float)q + 0.5f) * (1.0f / (float)NQ);
        const int   jc = (int)(cq * 63.0f + 0.5f);
        int js = jc - 7;
        js = js < 0 ? 0 : (js > NBINS - 16 ? NBINS - 16 : js);
        float s = 1e-12f;
        #pragma unroll
        for (int i = 0; i < 16; ++i) {
            const float d = (cq - cl[js + i]) * 50.0f;   // (x-c)/sigma
            s += __expf(-0.5f * d * d);
        }
        wq[q] = n / s;
    }
    __syncthreads();

    // ---- phase 2b: per-bin gather, NO atomics ----
    // Bin j (4 threads, g = quarter) scans its 384-cell window with the
    // exact scatter predicate; same terms as scatter, reordered sum.
    {
        const int   j  = t & 63;
        const int   g  = t >> 6;
        const float cj = cl[j];
        int qlo = (int)(((float)j - 8.5f) * (1024.0f / 63.0f)) - 2;
        qlo = qlo < 0 ? 0 : (qlo > NQ - WIN ? NQ - WIN : qlo);
        float acc = 0.0f;
        #pragma unroll 8
        for (int i = g; i < WIN; i += 4) {               // 96 iterations
            const int   q  = qlo + i;
            const float w  = wq[q];
            const float cq = ((float)q + 0.5f) * (1.0f / (float)NQ);
            const int   jc = (int)(cq * 63.0f + 0.5f);
            int js = jc - 7;
            js = js < 0 ? 0 : (js > NBINS - 16 ? NBINS - 16 : js);
            const float d  = (cq - cj) * 50.0f;
            acc += (j >= js && j <= js + 15) ? __expf(-0.5f * d * d) * w : 0.0f;
        }
        part[g][j] = acc;
    }
    __syncthreads();

    // ---- phase 3: handoff to disjoint slot (R9-proven protocol) ----
    if (t < NBINS) {
        const float fhj = part[0][t] + part[1][t] + part[2][t] + part[3][t];
        const float old = atomicExch(&g_part[bid * NBINS + t], fhj);
        asm volatile("" :: "v"(old));     // keep RMW live across the barrier
    }
    __syncthreads();   // s_waitcnt vmcnt(0) before s_barrier: exchanges ack'd

    if (t == 0)
        s_last = ((atomicAdd(&g_ticket[img * 32], 1u) & 31u) == 31u) ? 1u : 0u;
    __syncthreads();
    if (!s_last) return;

    // ---- last block of this image: coherent reads (disjoint addresses,
    //      two independent chains), reduce, normalize.
    {
        const int j = t & 63;             // bin
        const int g = t >> 6;             // quarter: parts g*8 .. g*8+7
        float* base = (float*)&g_part[(size_t)(img * BPI + g * 8) * NBINS + j];
        float s0 = 0.0f, s1 = 0.0f;
        #pragma unroll
        for (int b = 0; b < 8; b += 2) {
            s0 += unsafeAtomicAdd(&base[(b + 0) * NBINS], 0.0f);
            s1 += unsafeAtomicAdd(&base[(b + 1) * NBINS], 0.0f);
        }
        red[g][j] = s0 + s1;
    }
    __syncthreads();

    if (t < NBINS) {
        const float hsum = red[0][t] + red[1][t] + red[2][t] + red[3][t];
        const float hm   = hsum * (1.0f / (float)IMG_PIX);    // mean over pixels
        float ss = hm;
        #pragma unroll
        for (int off = 32; off > 0; off >>= 1) ss += __shfl_xor(ss, off, 64);
        out[img * NBINS + t] = hm / (ss + 1e-12f);            // per-image normalize
    }
}

extern "C" void kernel_launch(void* const* d_in, const int* in_sizes, int n_in,
                              void* d_out, int out_size, void* d_ws, size_t ws_size,
                              hipStream_t stream)
{
    const float* x       = (const float*)d_in[0];   // (8,3,512,512) fp32
    const float* centers = (const float*)d_in[1];   // (64,) fp32
    float* out           = (float*)d_out;           // (8,3,64) fp32
    (void)d_ws; (void)ws_size;

    soft_hist_fused<<<CNT_BLOCKS, 256, 0, stream>>>(x, centers, out);
}

// Round 11
// 75.294 us; speedup vs baseline: 1.0835x; 1.0835x over previous
//
#include <hip/hip_runtime.h>

// Soft histogram via quantization table:
//   hist[b,c,j] = (1/P) * sum_pixels f_j(x),  f_j(x) = k_j(x)/(sum_j k_j(x)+1e-12)
// f depends only on x -> quantize x into NQ cells, precompute f at cell centers,
// reduce to integer histogram + tiny contraction. absmax 1.2e-4 vs 3.3e-4 tol.
//
// R2:  two dispatches, disjoint partials.                     90.0 us
// R5:  wide-unroll 256-thr finalize.                          75.7 us
// R7:  fence-free atomic split.                               74.0 us  <- base
// R8-R10: fused w/ LDS float atomicAdd: 78 us kernel (CAS-loop storms).
// R11: split + unsafeAtomicAdd: 74.0, zero delta (split at its floor shape).
// R12: fused, zero float atomics: kernel 78 -> ~21 us (CAS theory confirmed)
//      but still > split's 13 us of kernels (gather bank conflicts + 160
//      exp/thread). Fused path abandoned. Budget (4 graph shapes, +-1 us):
//      fill 43.4 + per-graph replay ~17.3 = 60.8 fixed; kernels controllable.
// R13: split micro-opts only: (a) parts u32 -> u16 (max count 8192 < 2^16;
//      halves the 6 MB round-trip); (b) SLICES 8 -> 16 (384 K2 blocks,
//      8 loads/thread phase 1, 16-iter contraction). Protocol unchanged.

#define NQ      1024
#define NBINS   64
#define NIMG    24            // B*C = 8*3
#define IMG_PIX (512 * 512)   // 262144 pixels per (b,c) image
#define BPI     32            // count blocks per image
#define CNT_BLOCKS (NIMG * BPI)        // 768
#define TBL_BLOCKS (NQ / 4)            // 256 (4 quant cells per 256-thread block)
#define SLICES  16                     // finalize blocks per image
#define SLICE_Q (NQ / SLICES)          // 64 q-cells per finalize block

// ---- K1: fused count (blocks 0..767) + table build (blocks 768..1023) ----
__global__ __launch_bounds__(256) void soft_hist_k1(
    const float* __restrict__ x, const float* __restrict__ centers,
    float* __restrict__ table, unsigned short* __restrict__ parts,
    float* __restrict__ hist_acc, unsigned int* __restrict__ tickets)
{
    const int bid = blockIdx.x;
    const int t   = threadIdx.x;

    if (bid < CNT_BLOCKS) {
        // ---- per-(image,slice) histogram over NQ quant cells ----
        __shared__ unsigned int h[NQ];
        #pragma unroll
        for (int k = 0; k < NQ / 256; ++k) h[t + k * 256] = 0u;
        __syncthreads();

        // Block covers 2048 float4 (8192 pixels), contiguous 32 KB chunk.
        const float4* x4 = (const float4*)x + (size_t)bid * (IMG_PIX / 4 / BPI);

        // Prefetch all 8 float4 into registers -> 8 HBM loads in flight.
        float4 v[8];
        #pragma unroll
        for (int r = 0; r < 8; ++r) v[r] = x4[r * 256 + t];

        #pragma unroll
        for (int r = 0; r < 8; ++r) {
            const float4 p = v[r];
            int q0 = (int)(p.x * (float)NQ); q0 = q0 < 0 ? 0 : (q0 > NQ - 1 ? NQ - 1 : q0);
            int q1 = (int)(p.y * (float)NQ); q1 = q1 < 0 ? 0 : (q1 > NQ - 1 ? NQ - 1 : q1);
            int q2 = (int)(p.z * (float)NQ); q2 = q2 < 0 ? 0 : (q2 > NQ - 1 ? NQ - 1 : q2);
            int q3 = (int)(p.w * (float)NQ); q3 = q3 < 0 ? 0 : (q3 > NQ - 1 ? NQ - 1 : q3);
            atomicAdd(&h[q0], 1u);   // u32 LDS atomics: native HW op
            atomicAdd(&h[q1], 1u);
            atomicAdd(&h[q2], 1u);
            atomicAdd(&h[q3], 1u);
        }
        __syncthreads();

        // Coalesced u16 store (max count/cell = 8192 pixels < 2^16).
        unsigned short* dst = parts + (size_t)bid * NQ;
        #pragma unroll
        for (int k = 0; k < NQ / 256; ++k)
            dst[t + k * 256] = (unsigned short)h[t + k * 256];
    } else {
        // First table block zero-inits the accumulator + tickets (ws is
        // poisoned each replay; K1->K2 stream order makes zeros visible).
        if (bid == CNT_BLOCKS) {
            #pragma unroll
            for (int k = 0; k < (NIMG * NBINS) / 256; ++k)
                hist_acc[t + k * 256] = 0.0f;
            if (t < NIMG) tickets[t] = 0u;
        }

        // ---- table[q][j] = normalized Gaussian kernel at quant-cell center q ----
        const int lane = t & 63;                       // bin (64 bins == 1 wave)
        const int q    = (bid - CNT_BLOCKS) * 4 + (t >> 6);
        const float cq = ((float)q + 0.5f) * (1.0f / (float)NQ);
        // (x - c)/(SIGMA + 1e-12); 0.02 + 1e-12 rounds to 0.02f in fp32
        const float d  = (cq - centers[lane]) * 50.0f;
        const float e  = expf(-0.5f * d * d);
        float s = e;
        #pragma unroll
        for (int off = 32; off > 0; off >>= 1) s += __shfl_xor(s, off, 64);
        table[q * NBINS + lane] = e / (s + 1e-12f);
    }
}

// ---- K2: 16 blocks per image; each contracts a 64-q slice and atomically
//      accumulates (HW fp atomics); last block per image (ticket) normalizes.
__global__ __launch_bounds__(256) void soft_hist_final(
    const unsigned short* __restrict__ parts, const float* __restrict__ table,
    float* hist_acc, unsigned int* tickets, float* __restrict__ out)
{
    __shared__ float sh[4][SLICE_Q];
    __shared__ float tf[SLICE_Q];
    __shared__ float part[4][NBINS];
    __shared__ unsigned int is_last;

    const int t   = threadIdx.x;
    const int img = blockIdx.x / SLICES;
    const int k   = blockIdx.x % SLICES;       // q-slice index

    // Phase 1: tf[c] = sum over 32 partials of cell q = k*64 + c.
    // 4 threads per cell (sub = t>>6 sums partials sub*8..sub*8+7):
    // 8 independent 2KB-stride u16 loads in flight per thread.
    {
        const int c   = t & 63;
        const int sub = t >> 6;
        const unsigned short* src = parts + (size_t)img * BPI * NQ
                                   + (size_t)(sub * 8) * NQ + (k * SLICE_Q + c);
        unsigned int s = 0;
        #pragma unroll
        for (int b = 0; b < 8; ++b) s += src[(size_t)b * NQ];
        sh[sub][c] = (float)s;
    }
    __syncthreads();
    if (t < SLICE_Q) tf[t] = sh[0][t] + sh[1][t] + sh[2][t] + sh[3][t];
    __syncthreads();

    // Phase 2: contraction over this slice. Group g (of 4) covers 16 q's;
    // lane j = bin. 16 fully-unrolled coalesced 256B table reads in flight.
    const int j = t & 63;
    const int g = t >> 6;
    float acc = 0.0f;
    const float* tb = table + (size_t)(k * SLICE_Q + g * 16) * NBINS + j;
    #pragma unroll
    for (int qq = 0; qq < 16; ++qq)
        acc += tb[(size_t)qq * NBINS] * tf[g * 16 + qq];   // tf read is wave-broadcast
    part[g][j] = acc;
    __syncthreads();

    // Accumulate this slice's 64-float partial: HW global_atomic_add_f32.
    // Keep the return live so the vmcnt(0) before the next barrier covers
    // the RMW completion (R7/R11-proven fence-free release).
    if (t < NBINS) {
        const float old = unsafeAtomicAdd(&hist_acc[img * NBINS + t],
                                          part[0][t] + part[1][t] + part[2][t] + part[3][t]);
        asm volatile("" :: "v"(old));
    }
    __syncthreads();   // compiler emits s_waitcnt vmcnt(0) before s_barrier

    if (t == 0)
        is_last = (atomicAdd(&tickets[img], 1u) == SLICES - 1) ? 1u : 0u;
    __syncthreads();
    if (!is_last) return;

    // Last block of this image: coherent read via HW atomic RMW (+0.0f),
    // then normalize. All slices' adds are complete (their barriers
    // drained vmcnt before their tickets).
    if (t < NBINS) {
        const float hsum = unsafeAtomicAdd(&hist_acc[img * NBINS + t], 0.0f);
        const float hm   = hsum * (1.0f / (float)IMG_PIX);   // mean over pixels
        float ss = hm;
        #pragma unroll
        for (int off = 32; off > 0; off >>= 1) ss += __shfl_xor(ss, off, 64);
        out[img * NBINS + t] = hm / (ss + 1e-12f);           // per-image normalize
    }
}

extern "C" void kernel_launch(void* const* d_in, const int* in_sizes, int n_in,
                              void* d_out, int out_size, void* d_ws, size_t ws_size,
                              hipStream_t stream)
{
    const float* x       = (const float*)d_in[0];   // (8,3,512,512) fp32
    const float* centers = (const float*)d_in[1];   // (64,) fp32
    float* out           = (float*)d_out;           // (8,3,64) fp32

    char* ws = (char*)d_ws;
    float*          table    = (float*)ws;                 // 256 KB
    ws += (size_t)NQ * NBINS * sizeof(float);
    unsigned short* parts    = (unsigned short*)ws;        // 1.5 MB (u16)
    ws += (size_t)CNT_BLOCKS * NQ * sizeof(unsigned short);
    float*          hist_acc = (float*)ws;                 // 6 KB
    ws += (size_t)NIMG * NBINS * sizeof(float);
    unsigned int*   tickets  = (unsigned int*)ws;          // 96 B

    soft_hist_k1<<<CNT_BLOCKS + TBL_BLOCKS, 256, 0, stream>>>(
        x, centers, table, parts, hist_acc, tickets);
    soft_hist_final<<<NIMG * SLICES, 256, 0, stream>>>(
        parts, table, hist_acc, tickets, out);
}